// Round 5
// baseline (552.589 us; speedup 1.0000x reference)
//
#include <hip/hip_runtime.h>
#include <hip/hip_bf16.h>

#define N_NODES 50000
#define HEADS 8
#define CHANS 10
#define HC 80
#define PADC 12
#define PHC 96                // padded row stride for xl/xr (floats)
#define F_IN 128
#define E_EDGES 1600000
#define E_TOT (E_EDGES + N_NODES)
#define NEG_SLOPE 0.2f
#define NBUCK 3125            // 50000 / 16 exactly (16 nodes per bucket)
#define NCHUNK 256
#define CHUNK ((E_TOT + NCHUNK - 1) / NCHUNK)

// ---------------------------------------------------------------------------
__global__ void detect_mode_kernel(const void* ei, int* flag) {
    const int* p = (const int*)ei;
    int tid = threadIdx.x;
    bool ok = (p[2 * tid + 1] == 0) && (p[2 * (tid + 64) + 1] == 0);
    unsigned long long m = __ballot(ok);
    if (tid == 0) *flag = (m == ~0ull) ? 1 : 0;
}

__device__ inline void load_edge(const void* ei, int is64, int e, int& src, int& dst) {
    if (e < E_EDGES) {
        if (is64) {
            src = (int)((const long long*)ei)[e];
            dst = (int)((const long long*)ei)[E_EDGES + e];
        } else {
            src = ((const int*)ei)[e];
            dst = ((const int*)ei)[E_EDGES + e];
        }
    } else {
        src = dst = e - E_EDGES;
    }
}

__device__ inline int load_dst(const void* ei, int is64, int e) {
    if (e < E_EDGES) {
        if (is64) return (int)((const long long*)ei)[E_EDGES + e];
        return ((const int*)ei)[E_EDGES + e];
    }
    return e - E_EDGES;
}

// ---------------------------------------------------------------------------
// Phase 1: per-chunk bucket histogram. No global atomics.
__global__ __launch_bounds__(256) void hist_kernel(
        const void* ei, const int* __restrict__ flag, int* __restrict__ hist) {
    __shared__ int h[NBUCK];
    for (int i = threadIdx.x; i < NBUCK; i += 256) h[i] = 0;
    __syncthreads();
    int blk = blockIdx.x;
    int e0 = blk * CHUNK, e1 = min(e0 + CHUNK, E_TOT);
    int is64 = *flag;
    for (int e = e0 + threadIdx.x; e < e1; e += 4 * 256) {
        int d[4]; int cnt = 0;
        #pragma unroll
        for (int u = 0; u < 4; u++) {
            int ee = e + u * 256;
            if (ee < e1) { d[u] = load_dst(ei, is64, ee); cnt = u + 1; }
        }
        #pragma unroll
        for (int u = 0; u < 4; u++)
            if (u < cnt) atomicAdd(&h[d[u] >> 4], 1);
    }
    __syncthreads();
    for (int i = threadIdx.x; i < NBUCK; i += 256) hist[blk * NBUCK + i] = h[i];
}

// ---------------------------------------------------------------------------
__global__ __launch_bounds__(256) void colscan_kernel(
        int* __restrict__ hist, int* __restrict__ total) {
    int b = blockIdx.x * 256 + threadIdx.x;
    if (b >= NBUCK) return;
    int run = 0;
    for (int blk = 0; blk < NCHUNK; blk++) {
        int t = hist[blk * NBUCK + b];
        hist[blk * NBUCK + b] = run;
        run += t;
    }
    total[b] = run;
}

// ---------------------------------------------------------------------------
__global__ void scan_total_kernel(const int* __restrict__ total, int* __restrict__ bbase) {
    __shared__ int wsum[16];
    __shared__ int wpre[16];
    __shared__ int carry;
    int tid = threadIdx.x;
    int lane = tid & 63, w = tid >> 6;
    if (tid == 0) carry = 0;
    __syncthreads();
    for (int base = 0; base < NBUCK; base += 1024) {
        int idx = base + tid;
        int v = (idx < NBUCK) ? total[idx] : 0;
        int sv = v;
        #pragma unroll
        for (int off = 1; off < 64; off <<= 1) {
            int t = __shfl_up(sv, off, 64);
            if (lane >= off) sv += t;
        }
        if (lane == 63) wsum[w] = sv;
        __syncthreads();
        if (w == 0) {
            int s = (lane < 16) ? wsum[lane] : 0;
            #pragma unroll
            for (int off = 1; off < 16; off <<= 1) {
                int t = __shfl_up(s, off, 64);
                if (lane >= off) s += t;
            }
            if (lane < 16) wpre[lane] = s;
        }
        __syncthreads();
        int pre = carry + ((w > 0) ? wpre[w - 1] : 0);
        if (idx < NBUCK) bbase[idx] = pre + sv - v;
        __syncthreads();
        if (tid == 0) carry += wpre[15];
        __syncthreads();
    }
}

// ---------------------------------------------------------------------------
// Phase 3: deterministic-placement scatter into 16-node buckets. LDS cursors only.
__global__ __launch_bounds__(256) void scatter_sort_kernel(
        const void* ei, const int* __restrict__ flag,
        const int* __restrict__ hist, const int* __restrict__ bbase,
        int* __restrict__ tmp) {
    __shared__ int cur[NBUCK];
    int blk = blockIdx.x;
    for (int i = threadIdx.x; i < NBUCK; i += 256)
        cur[i] = bbase[i] + hist[blk * NBUCK + i];
    __syncthreads();
    int e0 = blk * CHUNK, e1 = min(e0 + CHUNK, E_TOT);
    int is64 = *flag;
    for (int e = e0 + threadIdx.x; e < e1; e += 4 * 256) {
        int s[4], d[4]; int cnt = 0;
        #pragma unroll
        for (int u = 0; u < 4; u++) {
            int ee = e + u * 256;
            if (ee < e1) { load_edge(ei, is64, ee, s[u], d[u]); cnt = u + 1; }
        }
        #pragma unroll
        for (int u = 0; u < 4; u++) {
            if (u < cnt) {
                int pos = atomicAdd(&cur[d[u] >> 4], 1);
                tmp[pos] = (s[u] << 4) | (d[u] & 15);
            }
        }
    }
}

// ---------------------------------------------------------------------------
// Phase 4 (build, once): bucket-grouped tmp -> node-grouped adj + nstart + deg.
__global__ __launch_bounds__(256) void node_sort_kernel(
        const int* __restrict__ tmp, const int* __restrict__ bbase,
        const int* __restrict__ total,
        int* __restrict__ adj, int* __restrict__ nstart, int* __restrict__ deg) {
    __shared__ int h16[16];
    __shared__ int st16[16];
    __shared__ int cur16[16];
    int tid = threadIdx.x;
    int b = blockIdx.x;
    int base = bbase[b];
    int n = total[b];
    if (tid < 16) h16[tid] = 0;
    __syncthreads();
    for (int k = tid; k < n; k += 256)
        atomicAdd(&h16[tmp[base + k] & 15], 1);
    __syncthreads();
    if (tid == 0) {
        int run = 0;
        #pragma unroll
        for (int c = 0; c < 16; c++) { st16[c] = run; cur16[c] = run; run += h16[c]; }
    }
    __syncthreads();
    for (int k = tid; k < n; k += 256) {
        int p = tmp[base + k];
        int pos = atomicAdd(&cur16[p & 15], 1);
        adj[base + pos] = p >> 4;
    }
    if (tid < 16) {
        nstart[b * 16 + tid] = base + st16[tid];
        deg[b * 16 + tid] = h16[tid];
    }
}

// ---------------------------------------------------------------------------
// Degree-balanced node permutation: counting sort by min(deg,255).
__global__ __launch_bounds__(256) void deghist_kernel(
        const int* __restrict__ deg, int* __restrict__ dh) {
    __shared__ int h[256];
    h[threadIdx.x] = 0;
    __syncthreads();
    int i = blockIdx.x * 256 + threadIdx.x;
    if (i < N_NODES) atomicAdd(&h[min(deg[i], 255)], 1);
    __syncthreads();
    if (h[threadIdx.x]) atomicAdd(&dh[threadIdx.x], h[threadIdx.x]);
}

__global__ void degscan_kernel(const int* __restrict__ dh, int* __restrict__ dcur) {
    __shared__ int s[256];
    int tid = threadIdx.x;
    int own = dh[tid];
    s[tid] = own;
    __syncthreads();
    for (int off = 1; off < 256; off <<= 1) {
        int t = (tid >= off) ? s[tid - off] : 0;
        __syncthreads();
        s[tid] += t;
        __syncthreads();
    }
    dcur[tid] = s[tid] - own;   // exclusive
}

__global__ __launch_bounds__(256) void degscatter_kernel(
        const int* __restrict__ deg, int* __restrict__ dcur, int* __restrict__ perm) {
    __shared__ int h[256];
    __shared__ int res[256];
    __shared__ int lc[256];
    int tid = threadIdx.x;
    h[tid] = 0; lc[tid] = 0;
    __syncthreads();
    int i = blockIdx.x * 256 + tid;
    int d = (i < N_NODES) ? min(deg[i], 255) : -1;
    if (d >= 0) atomicAdd(&h[d], 1);
    __syncthreads();
    res[tid] = h[tid] ? atomicAdd(&dcur[tid], h[tid]) : 0;
    __syncthreads();
    if (d >= 0) {
        int off = atomicAdd(&lc[d], 1);
        perm[res[d] + off] = i;
    }
}

// ---------------------------------------------------------------------------
// xl = x @ Wl, xr = x @ Wr (padded output rows, PHC floats).
// Block 256, tile 128 nodes x 160 cols, 8 nodes x 10 cols per thread.
__global__ __launch_bounds__(256) void gemm_xlxr_kernel(
        const float* __restrict__ x, const float* __restrict__ wl,
        const float* __restrict__ wr, int din,
        float* __restrict__ xl, float* __restrict__ xr) {
    __shared__ float xs[16 * 128];   // [k][node]
    __shared__ float ws[16 * 160];   // [k][col]
    int tid = threadIdx.x;
    int n0 = blockIdx.x * 128;
    int tn = tid >> 4;          // 0..15 -> nodes tn*8..tn*8+7
    int tc = tid & 15;          // col chunk tc*10
    float acc[8][10];
    #pragma unroll
    for (int i = 0; i < 8; i++)
        #pragma unroll
        for (int j = 0; j < 10; j++) acc[i][j] = 0.f;

    int nkt = din >> 4;
    int lr = tid >> 1;          // node 0..127
    int lc = (tid & 1) * 8;     // k offset 0 or 8

    for (int kt = 0; kt < nkt; kt++) {
        float4 a0 = make_float4(0.f, 0.f, 0.f, 0.f), a1 = a0;
        int n = n0 + lr;
        if (n < N_NODES) {
            a0 = *(const float4*)(x + (size_t)n * din + kt * 16 + lc);
            a1 = *(const float4*)(x + (size_t)n * din + kt * 16 + lc + 4);
        }
        __syncthreads();   // protect previous iteration's LDS reads
        xs[(lc + 0) * 128 + lr] = a0.x;
        xs[(lc + 1) * 128 + lr] = a0.y;
        xs[(lc + 2) * 128 + lr] = a0.z;
        xs[(lc + 3) * 128 + lr] = a0.w;
        xs[(lc + 4) * 128 + lr] = a1.x;
        xs[(lc + 5) * 128 + lr] = a1.y;
        xs[(lc + 6) * 128 + lr] = a1.z;
        xs[(lc + 7) * 128 + lr] = a1.w;
        #pragma unroll
        for (int rep = 0; rep < 10; rep++) {
            int flat = rep * 256 + tid;
            int k = flat / 160, c = flat % 160;
            int kg = kt * 16 + k;
            float wv = (c < 80) ? wl[kg * 80 + c] : wr[kg * 80 + (c - 80)];
            ws[k * 160 + c] = wv;
        }
        __syncthreads();
        #pragma unroll
        for (int k = 0; k < 16; k++) {
            float4 x0 = *(const float4*)(&xs[k * 128 + tn * 8]);
            float4 x1 = *(const float4*)(&xs[k * 128 + tn * 8 + 4]);
            float xa[8] = {x0.x, x0.y, x0.z, x0.w, x1.x, x1.y, x1.z, x1.w};
            #pragma unroll
            for (int j = 0; j < 10; j++) {
                float wv = ws[k * 160 + tc * 10 + j];
                #pragma unroll
                for (int i = 0; i < 8; i++) acc[i][j] += xa[i] * wv;
            }
        }
    }
    float* outp = (tc < 8) ? xl : xr;
    int cbase = (tc & 7) * PADC;
    #pragma unroll
    for (int i = 0; i < 8; i++) {
        int n = n0 + tn * 8 + i;
        if (n < N_NODES) {
            #pragma unroll
            for (int j = 0; j < 10; j++)
                outp[(size_t)n * PHC + cbase + j] = acc[i][j];
        }
    }
}

// ---------------------------------------------------------------------------
// Online-softmax aggregation over per-node CSR. Block = 16 nodes (degree-
// sorted via perm) x 8 heads x 2 splits. Batch-4 gathers for ILP; padded
// xl/xr rows give float4-aligned value loads.
__global__ __launch_bounds__(256) void agg_kernel(
        const float* __restrict__ xl, const float* __restrict__ xr,
        const float* __restrict__ att, const float* __restrict__ bias,
        const int* __restrict__ nstart, const int* __restrict__ deg,
        const int* __restrict__ adj, const int* __restrict__ perm,
        float* __restrict__ y) {
    int tid = threadIdx.x;
    int b = blockIdx.x;
    int h = tid & 7;
    int split = (tid >> 3) & 1;
    int i_local = tid >> 4;
    int node = perm[b * 16 + i_local];

    int s0 = nstart[node];
    int dg = deg[node];
    int cnt_s = (dg > split) ? ((dg - split + 1) >> 1) : 0;
    int k0 = s0 + split;

    float xr_c[CHANS], att_c[CHANS];
    {
        const float4* q = (const float4*)(xr + (size_t)node * PHC + h * PADC);
        float4 r0 = q[0], r1 = q[1];
        float2 r2 = *(const float2*)(xr + (size_t)node * PHC + h * PADC + 8);
        xr_c[0]=r0.x; xr_c[1]=r0.y; xr_c[2]=r0.z; xr_c[3]=r0.w;
        xr_c[4]=r1.x; xr_c[5]=r1.y; xr_c[6]=r1.z; xr_c[7]=r1.w;
        xr_c[8]=r2.x; xr_c[9]=r2.y;
    }
    #pragma unroll
    for (int c = 0; c < CHANS; c++) att_c[c] = att[h * CHANS + c];

    float m = -INFINITY, l = 0.f;
    float acc[CHANS];
    #pragma unroll
    for (int c = 0; c < CHANS; c++) acc[c] = 0.f;

    auto load_row = [&](int j, float* v) {
        const float4* p = (const float4*)(xl + (size_t)j * PHC + h * PADC);
        float4 a = p[0], bq = p[1];
        float2 cq = *(const float2*)(xl + (size_t)j * PHC + h * PADC + 8);
        v[0]=a.x; v[1]=a.y; v[2]=a.z; v[3]=a.w;
        v[4]=bq.x; v[5]=bq.y; v[6]=bq.z; v[7]=bq.w;
        v[8]=cq.x; v[9]=cq.y;
    };
    auto score_of = [&](const float* v) {
        float s = 0.f;
        #pragma unroll
        for (int c = 0; c < CHANS; c++) {
            float t = v[c] + xr_c[c];
            t = (t > 0.f) ? t : NEG_SLOPE * t;
            s += att_c[c] * t;
        }
        return s;
    };

    int kk = 0;
    for (; kk + 4 <= cnt_s; kk += 4) {
        int j0 = adj[k0 + 2 * (kk + 0)];
        int j1 = adj[k0 + 2 * (kk + 1)];
        int j2 = adj[k0 + 2 * (kk + 2)];
        int j3 = adj[k0 + 2 * (kk + 3)];
        float v0[CHANS], v1[CHANS], v2[CHANS], v3[CHANS];
        load_row(j0, v0); load_row(j1, v1); load_row(j2, v2); load_row(j3, v3);
        float s0s = score_of(v0), s1s = score_of(v1);
        float s2s = score_of(v2), s3s = score_of(v3);
        float mb = fmaxf(fmaxf(fmaxf(s0s, s1s), fmaxf(s2s, s3s)), m);
        float scale = __expf(m - mb);
        float p0 = __expf(s0s - mb), p1 = __expf(s1s - mb);
        float p2 = __expf(s2s - mb), p3 = __expf(s3s - mb);
        l = l * scale + p0 + p1 + p2 + p3;
        #pragma unroll
        for (int c = 0; c < CHANS; c++)
            acc[c] = acc[c] * scale + p0 * v0[c] + p1 * v1[c] + p2 * v2[c] + p3 * v3[c];
        m = mb;
    }
    for (; kk < cnt_s; kk++) {
        int j = adj[k0 + 2 * kk];
        float v[CHANS];
        load_row(j, v);
        float s = score_of(v);
        float mn = fmaxf(m, s);
        float scale = __expf(m - mn);
        float p = __expf(s - mn);
        l = l * scale + p;
        #pragma unroll
        for (int c = 0; c < CHANS; c++) acc[c] = acc[c] * scale + p * v[c];
        m = mn;
    }

    // merge the two splits (partner 8 lanes away, same wave)
    float m2 = __shfl_xor(m, 8, 64);
    float l2 = __shfl_xor(l, 8, 64);
    float mn = fmaxf(m, m2);
    float sc1 = __expf(m - mn), sc2 = __expf(m2 - mn);
    float lt = l * sc1 + l2 * sc2;
    float accm[CHANS];
    #pragma unroll
    for (int c = 0; c < CHANS; c++) {
        float a2 = __shfl_xor(acc[c], 8, 64);
        accm[c] = acc[c] * sc1 + a2 * sc2;
    }
    if (split == 0) {
        float inv = 1.f / (lt + 1e-16f);
        #pragma unroll
        for (int c = 0; c < CHANS; c++) {
            float z = accm[c] * inv + bias[h * CHANS + c];
            y[(size_t)node * HC + h * CHANS + c] = (z > 0.f) ? z : (__expf(z) - 1.f);
        }
    }
}

// ---------------------------------------------------------------------------
extern "C" void kernel_launch(void* const* d_in, const int* in_sizes, int n_in,
                              void* d_out, int out_size, void* d_ws, size_t ws_size,
                              hipStream_t stream) {
    const float* x_in = (const float*)d_in[0];
    const void*  ei   = d_in[1];
    const float* Wl[3] = {(const float*)d_in[2], (const float*)d_in[6],  (const float*)d_in[10]};
    const float* Wr[3] = {(const float*)d_in[3], (const float*)d_in[7],  (const float*)d_in[11]};
    const float* At[3] = {(const float*)d_in[4], (const float*)d_in[8],  (const float*)d_in[12]};
    const float* Bi[3] = {(const float*)d_in[5], (const float*)d_in[9],  (const float*)d_in[13]};
    float* out = (float*)d_out;

    char* ws = (char*)d_ws;
    size_t off = 0;
    auto alloc = [&](size_t bytes) {
        void* p = ws + off;
        off += (bytes + 255) & ~(size_t)255;
        return p;
    };
    float* xl     = (float*)alloc((size_t)N_NODES * PHC * sizeof(float));
    float* xr     = (float*)alloc((size_t)N_NODES * PHC * sizeof(float));
    float* buf    = (float*)alloc((size_t)N_NODES * HC * sizeof(float));
    int*   tmp    = (int*)alloc((size_t)E_TOT * sizeof(int));
    int*   adj    = (int*)alloc((size_t)E_TOT * sizeof(int));
    int*   hist   = (int*)alloc((size_t)NCHUNK * NBUCK * sizeof(int));
    int*   total  = (int*)alloc((size_t)NBUCK * sizeof(int));
    int*   bbase  = (int*)alloc((size_t)NBUCK * sizeof(int));
    int*   nstart = (int*)alloc((size_t)N_NODES * sizeof(int));
    int*   deg    = (int*)alloc((size_t)N_NODES * sizeof(int));
    int*   perm   = (int*)alloc((size_t)N_NODES * sizeof(int));
    int*   dh     = (int*)alloc(256 * sizeof(int));
    int*   dcur   = (int*)alloc(256 * sizeof(int));
    int*   flag   = (int*)alloc(256);

    // --- build per-node CSR + degree-sorted permutation (once per launch) ---
    detect_mode_kernel<<<1, 64, 0, stream>>>(ei, flag);
    hist_kernel<<<NCHUNK, 256, 0, stream>>>(ei, flag, hist);
    colscan_kernel<<<(NBUCK + 255) / 256, 256, 0, stream>>>(hist, total);
    scan_total_kernel<<<1, 1024, 0, stream>>>(total, bbase);
    scatter_sort_kernel<<<NCHUNK, 256, 0, stream>>>(ei, flag, hist, bbase, tmp);
    node_sort_kernel<<<NBUCK, 256, 0, stream>>>(tmp, bbase, total, adj, nstart, deg);
    hipMemsetAsync(dh, 0, 256 * sizeof(int), stream);
    int nblocks = (N_NODES + 255) / 256;
    deghist_kernel<<<nblocks, 256, 0, stream>>>(deg, dh);
    degscan_kernel<<<1, 256, 0, stream>>>(dh, dcur);
    degscatter_kernel<<<nblocks, 256, 0, stream>>>(deg, dcur, perm);

    // --- 3 GATv2 layers ---
    int gemm_blocks = (N_NODES + 127) / 128;
    const float* cur = x_in;
    int din = F_IN;
    for (int layer = 0; layer < 3; layer++) {
        gemm_xlxr_kernel<<<gemm_blocks, 256, 0, stream>>>(cur, Wl[layer], Wr[layer],
                                                          din, xl, xr);
        float* y = (layer == 2) ? out : buf;
        agg_kernel<<<NBUCK, 256, 0, stream>>>(xl, xr, At[layer], Bi[layer],
                                              nstart, deg, adj, perm, y);
        cur = buf;
        din = HC;
    }
}

// Round 6
// 422.060 us; speedup vs baseline: 1.3093x; 1.3093x over previous
//
#include <hip/hip_runtime.h>
#include <hip/hip_bf16.h>
#include <hip/hip_fp16.h>

#define N_NODES 50000
#define HEADS 8
#define CHANS 10
#define HC 80
#define PADH 12               // halfs per head chunk in xl (24 B)
#define PHL 96                // xl row stride in halfs (192 B)
#define F_IN 128
#define E_EDGES 1600000
#define E_TOT (E_EDGES + N_NODES)
#define NEG_SLOPE 0.2f
#define NBUCK 3125            // 50000 / 16 (16 nodes per bucket)
#define NCHUNK 128
#define CHUNK ((E_TOT + NCHUNK - 1) / NCHUNK)

__device__ inline void load_edge(const void* ei, int is64, int e, int& src, int& dst) {
    if (e < E_EDGES) {
        if (is64) {
            src = ((const int*)ei)[2 * e];            // little-endian low word
            dst = ((const int*)ei)[2 * (E_EDGES + e)];
        } else {
            src = ((const int*)ei)[e];
            dst = ((const int*)ei)[E_EDGES + e];
        }
    } else {
        src = dst = e - E_EDGES;
    }
}

__device__ inline int load_dst(const void* ei, int is64, int e) {
    if (e < E_EDGES) {
        if (is64) return ((const int*)ei)[2 * (E_EDGES + e)];
        return ((const int*)ei)[E_EDGES + e];
    }
    return e - E_EDGES;
}

// detect int64-vs-int32 edge_index inside the block (wave 0), no extra kernel
__device__ inline int detect_is64(const void* ei, int tid, int* s_flag) {
    if (tid < 64) {
        const int* p = (const int*)ei;
        bool ok = (p[2 * tid + 1] == 0) && (p[2 * (tid + 64) + 1] == 0);
        unsigned long long m = __ballot(ok);
        if (tid == 0) *s_flag = (m == ~0ull) ? 1 : 0;
    }
    return 0;
}

// ---------------------------------------------------------------------------
// Phase 1: per-chunk bucket histogram. No global atomics.
__global__ __launch_bounds__(256) void hist_kernel(
        const void* ei, int* __restrict__ hist) {
    __shared__ int h[NBUCK];
    __shared__ int s_is64;
    int tid = threadIdx.x;
    for (int i = tid; i < NBUCK; i += 256) h[i] = 0;
    detect_is64(ei, tid, &s_is64);
    __syncthreads();
    int is64 = s_is64;
    int blk = blockIdx.x;
    int e0 = blk * CHUNK, e1 = min(e0 + CHUNK, E_TOT);
    for (int e = e0 + tid; e < e1; e += 4 * 256) {
        int d[4]; int cnt = 0;
        #pragma unroll
        for (int u = 0; u < 4; u++) {
            int ee = e + u * 256;
            if (ee < e1) { d[u] = load_dst(ei, is64, ee); cnt = u + 1; }
        }
        #pragma unroll
        for (int u = 0; u < 4; u++)
            if (u < cnt) atomicAdd(&h[d[u] >> 4], 1);
    }
    __syncthreads();
    for (int i = tid; i < NBUCK; i += 256) hist[blk * NBUCK + i] = h[i];
}

// ---------------------------------------------------------------------------
__global__ __launch_bounds__(256) void colscan_kernel(
        int* __restrict__ hist, int* __restrict__ total) {
    int b = blockIdx.x * 256 + threadIdx.x;
    if (b >= NBUCK) return;
    int run = 0;
    for (int blk = 0; blk < NCHUNK; blk++) {
        int t = hist[blk * NBUCK + b];
        hist[blk * NBUCK + b] = run;
        run += t;
    }
    total[b] = run;
}

// ---------------------------------------------------------------------------
__global__ void scan_total_kernel(const int* __restrict__ total, int* __restrict__ bbase) {
    __shared__ int wsum[16];
    __shared__ int wpre[16];
    __shared__ int carry;
    int tid = threadIdx.x;
    int lane = tid & 63, w = tid >> 6;
    if (tid == 0) carry = 0;
    __syncthreads();
    for (int base = 0; base < NBUCK; base += 1024) {
        int idx = base + tid;
        int v = (idx < NBUCK) ? total[idx] : 0;
        int sv = v;
        #pragma unroll
        for (int off = 1; off < 64; off <<= 1) {
            int t = __shfl_up(sv, off, 64);
            if (lane >= off) sv += t;
        }
        if (lane == 63) wsum[w] = sv;
        __syncthreads();
        if (w == 0) {
            int s = (lane < 16) ? wsum[lane] : 0;
            #pragma unroll
            for (int off = 1; off < 16; off <<= 1) {
                int t = __shfl_up(s, off, 64);
                if (lane >= off) s += t;
            }
            if (lane < 16) wpre[lane] = s;
        }
        __syncthreads();
        int pre = carry + ((w > 0) ? wpre[w - 1] : 0);
        if (idx < NBUCK) bbase[idx] = pre + sv - v;
        __syncthreads();
        if (tid == 0) carry += wpre[15];
        __syncthreads();
    }
}

// ---------------------------------------------------------------------------
// Phase 3: deterministic-placement scatter into 16-node buckets. LDS cursors only.
__global__ __launch_bounds__(256) void scatter_sort_kernel(
        const void* ei, const int* __restrict__ hist, const int* __restrict__ bbase,
        int* __restrict__ tmp) {
    __shared__ int cur[NBUCK];
    __shared__ int s_is64;
    int tid = threadIdx.x;
    int blk = blockIdx.x;
    for (int i = tid; i < NBUCK; i += 256)
        cur[i] = bbase[i] + hist[blk * NBUCK + i];
    detect_is64(ei, tid, &s_is64);
    __syncthreads();
    int is64 = s_is64;
    int e0 = blk * CHUNK, e1 = min(e0 + CHUNK, E_TOT);
    for (int e = e0 + tid; e < e1; e += 4 * 256) {
        int s[4], d[4]; int cnt = 0;
        #pragma unroll
        for (int u = 0; u < 4; u++) {
            int ee = e + u * 256;
            if (ee < e1) { load_edge(ei, is64, ee, s[u], d[u]); cnt = u + 1; }
        }
        #pragma unroll
        for (int u = 0; u < 4; u++) {
            if (u < cnt) {
                int pos = atomicAdd(&cur[d[u] >> 4], 1);
                tmp[pos] = (s[u] << 4) | (d[u] & 15);
            }
        }
    }
}

// ---------------------------------------------------------------------------
// Phase 4: bucket-grouped tmp -> node-grouped adj + nstart + deg.
__global__ __launch_bounds__(256) void node_sort_kernel(
        const int* __restrict__ tmp, const int* __restrict__ bbase,
        const int* __restrict__ total,
        int* __restrict__ adj, int* __restrict__ nstart, int* __restrict__ deg) {
    __shared__ int h16[16];
    __shared__ int st16[16];
    __shared__ int cur16[16];
    int tid = threadIdx.x;
    int b = blockIdx.x;
    int base = bbase[b];
    int n = total[b];
    if (tid < 16) h16[tid] = 0;
    __syncthreads();
    for (int k = tid; k < n; k += 256)
        atomicAdd(&h16[tmp[base + k] & 15], 1);
    __syncthreads();
    if (tid == 0) {
        int run = 0;
        #pragma unroll
        for (int c = 0; c < 16; c++) { st16[c] = run; cur16[c] = run; run += h16[c]; }
    }
    __syncthreads();
    for (int k = tid; k < n; k += 256) {
        int p = tmp[base + k];
        int pos = atomicAdd(&cur16[p & 15], 1);
        adj[base + pos] = p >> 4;
    }
    if (tid < 16) {
        nstart[b * 16 + tid] = base + st16[tid];
        deg[b * 16 + tid] = h16[tid];
    }
}

// ---------------------------------------------------------------------------
// Degree-balanced node permutation: counting sort by min(deg,255).
__global__ __launch_bounds__(256) void deghist_kernel(
        const int* __restrict__ deg, int* __restrict__ dh) {
    __shared__ int h[256];
    h[threadIdx.x] = 0;
    __syncthreads();
    int i = blockIdx.x * 256 + threadIdx.x;
    if (i < N_NODES) atomicAdd(&h[min(deg[i], 255)], 1);
    __syncthreads();
    if (h[threadIdx.x]) atomicAdd(&dh[threadIdx.x], h[threadIdx.x]);
}

__global__ void degscan_kernel(const int* __restrict__ dh, int* __restrict__ dcur) {
    __shared__ int s[256];
    int tid = threadIdx.x;
    int own = dh[tid];
    s[tid] = own;
    __syncthreads();
    for (int off = 1; off < 256; off <<= 1) {
        int t = (tid >= off) ? s[tid - off] : 0;
        __syncthreads();
        s[tid] += t;
        __syncthreads();
    }
    dcur[tid] = s[tid] - own;   // exclusive
}

__global__ __launch_bounds__(256) void degscatter_kernel(
        const int* __restrict__ deg, int* __restrict__ dcur, int* __restrict__ perm) {
    __shared__ int h[256];
    __shared__ int res[256];
    __shared__ int lc[256];
    int tid = threadIdx.x;
    h[tid] = 0; lc[tid] = 0;
    __syncthreads();
    int i = blockIdx.x * 256 + tid;
    int d = (i < N_NODES) ? min(deg[i], 255) : -1;
    if (d >= 0) atomicAdd(&h[d], 1);
    __syncthreads();
    res[tid] = h[tid] ? atomicAdd(&dcur[tid], h[tid]) : 0;
    __syncthreads();
    if (d >= 0) {
        int off = atomicAdd(&lc[d], 1);
        perm[res[d] + off] = i;
    }
}

// ---------------------------------------------------------------------------
// xl = x @ Wl -> fp16 padded rows (PHL halfs); xr = x @ Wr -> fp32 dense.
// Block 256, tile 128 nodes x 160 cols, 8 nodes x 10 cols per thread.
__global__ __launch_bounds__(256) void gemm_xlxr_kernel(
        const float* __restrict__ x, const float* __restrict__ wl,
        const float* __restrict__ wr, int din,
        __half* __restrict__ xlh, float* __restrict__ xr) {
    __shared__ float xs[16 * 128];   // [k][node]
    __shared__ float ws[16 * 160];   // [k][col]
    int tid = threadIdx.x;
    int n0 = blockIdx.x * 128;
    int tn = tid >> 4;          // 0..15 -> nodes tn*8..tn*8+7
    int tc = tid & 15;          // col chunk tc*10
    float acc[8][10];
    #pragma unroll
    for (int i = 0; i < 8; i++)
        #pragma unroll
        for (int j = 0; j < 10; j++) acc[i][j] = 0.f;

    int nkt = din >> 4;
    int lr = tid >> 1;          // node 0..127
    int lc = (tid & 1) * 8;     // k offset 0 or 8

    for (int kt = 0; kt < nkt; kt++) {
        float4 a0 = make_float4(0.f, 0.f, 0.f, 0.f), a1 = a0;
        int n = n0 + lr;
        if (n < N_NODES) {
            a0 = *(const float4*)(x + (size_t)n * din + kt * 16 + lc);
            a1 = *(const float4*)(x + (size_t)n * din + kt * 16 + lc + 4);
        }
        __syncthreads();   // protect previous iteration's LDS reads
        xs[(lc + 0) * 128 + lr] = a0.x;
        xs[(lc + 1) * 128 + lr] = a0.y;
        xs[(lc + 2) * 128 + lr] = a0.z;
        xs[(lc + 3) * 128 + lr] = a0.w;
        xs[(lc + 4) * 128 + lr] = a1.x;
        xs[(lc + 5) * 128 + lr] = a1.y;
        xs[(lc + 6) * 128 + lr] = a1.z;
        xs[(lc + 7) * 128 + lr] = a1.w;
        #pragma unroll
        for (int rep = 0; rep < 10; rep++) {
            int flat = rep * 256 + tid;
            int k = flat / 160, c = flat % 160;
            int kg = kt * 16 + k;
            float wv = (c < 80) ? wl[kg * 80 + c] : wr[kg * 80 + (c - 80)];
            ws[k * 160 + c] = wv;
        }
        __syncthreads();
        #pragma unroll
        for (int k = 0; k < 16; k++) {
            float4 x0 = *(const float4*)(&xs[k * 128 + tn * 8]);
            float4 x1 = *(const float4*)(&xs[k * 128 + tn * 8 + 4]);
            float xa[8] = {x0.x, x0.y, x0.z, x0.w, x1.x, x1.y, x1.z, x1.w};
            #pragma unroll
            for (int j = 0; j < 10; j++) {
                float wv = ws[k * 160 + tc * 10 + j];
                #pragma unroll
                for (int i = 0; i < 8; i++) acc[i][j] += xa[i] * wv;
            }
        }
    }
    if (tc < 8) {
        // xl -> fp16 padded, 5 packed uint stores per node
        #pragma unroll
        for (int i = 0; i < 8; i++) {
            int n = n0 + tn * 8 + i;
            if (n < N_NODES) {
                unsigned int* dst = (unsigned int*)(xlh + (size_t)n * PHL + tc * PADH);
                #pragma unroll
                for (int j = 0; j < 5; j++) {
                    __half2 hp = __halves2half2(__float2half_rn(acc[i][2 * j]),
                                                __float2half_rn(acc[i][2 * j + 1]));
                    dst[j] = *(unsigned int*)&hp;
                }
            }
        }
    } else {
        int cbase = (tc - 8) * 10;
        #pragma unroll
        for (int i = 0; i < 8; i++) {
            int n = n0 + tn * 8 + i;
            if (n < N_NODES) {
                #pragma unroll
                for (int j = 0; j < 10; j++)
                    xr[(size_t)n * HC + cbase + j] = acc[i][j];
            }
        }
    }
}

// ---------------------------------------------------------------------------
__device__ inline void cvt10(uint2 a, uint2 b, uint2 c, float* v) {
    __half2 h;
    h = *(__half2*)&a.x; v[0] = __low2float(h); v[1] = __high2float(h);
    h = *(__half2*)&a.y; v[2] = __low2float(h); v[3] = __high2float(h);
    h = *(__half2*)&b.x; v[4] = __low2float(h); v[5] = __high2float(h);
    h = *(__half2*)&b.y; v[6] = __low2float(h); v[7] = __high2float(h);
    h = *(__half2*)&c.x; v[8] = __low2float(h); v[9] = __high2float(h);
}

// Online-softmax aggregation. Block = 16 nodes (degree-sorted) x 8 heads x 2
// contiguous splits. fp16 xl rows (192 B), batch-8 packed gathers for ILP.
__global__ __launch_bounds__(256, 4) void agg_kernel(
        const __half* __restrict__ xlh, const float* __restrict__ xr,
        const float* __restrict__ att, const float* __restrict__ bias,
        const int* __restrict__ nstart, const int* __restrict__ deg,
        const int* __restrict__ adj, const int* __restrict__ perm,
        float* __restrict__ y) {
    int tid = threadIdx.x;
    int b = blockIdx.x;
    int h = tid & 7;
    int split = (tid >> 3) & 1;
    int i_local = tid >> 4;
    int node = perm[b * 16 + i_local];

    int s0 = nstart[node];
    int dg = deg[node];
    int cnt0 = (dg + 1) >> 1;
    int cnt = split ? (dg - cnt0) : cnt0;
    int k0 = s0 + split * cnt0;

    float xr_c[CHANS], att_c[CHANS];
    #pragma unroll
    for (int c = 0; c < CHANS; c++) {
        xr_c[c]  = xr[(size_t)node * HC + h * CHANS + c];
        att_c[c] = att[h * CHANS + c];
    }

    float m = -INFINITY, l = 0.f;
    float acc[CHANS];
    #pragma unroll
    for (int c = 0; c < CHANS; c++) acc[c] = 0.f;

    auto score10 = [&](const float* v) {
        float s = 0.f;
        #pragma unroll
        for (int c = 0; c < CHANS; c++) {
            float t = v[c] + xr_c[c];
            t = (t > 0.f) ? t : NEG_SLOPE * t;
            s += att_c[c] * t;
        }
        return s;
    };

    int kk = 0;
    for (; kk + 8 <= cnt; kk += 8) {
        uint2 ra[8], rb[8], rc[8];
        #pragma unroll
        for (int r = 0; r < 8; r++) {
            int j = adj[k0 + kk + r];
            const uint2* p = (const uint2*)(xlh + (size_t)j * PHL + h * PADH);
            ra[r] = p[0]; rb[r] = p[1]; rc[r] = p[2];
        }
        float sc[8];
        #pragma unroll
        for (int r = 0; r < 8; r++) {
            float v[CHANS];
            cvt10(ra[r], rb[r], rc[r], v);
            sc[r] = score10(v);
        }
        float mb = m;
        #pragma unroll
        for (int r = 0; r < 8; r++) mb = fmaxf(mb, sc[r]);
        float scale = __expf(m - mb);
        float ps = 0.f;
        #pragma unroll
        for (int r = 0; r < 8; r++) { sc[r] = __expf(sc[r] - mb); ps += sc[r]; }
        l = l * scale + ps;
        #pragma unroll
        for (int c = 0; c < CHANS; c++) acc[c] *= scale;
        #pragma unroll
        for (int r = 0; r < 8; r++) {
            float v[CHANS];
            cvt10(ra[r], rb[r], rc[r], v);
            #pragma unroll
            for (int c = 0; c < CHANS; c++) acc[c] += sc[r] * v[c];
        }
        m = mb;
    }
    for (; kk < cnt; kk++) {
        int j = adj[k0 + kk];
        const uint2* p = (const uint2*)(xlh + (size_t)j * PHL + h * PADH);
        uint2 a = p[0], bq = p[1], cq = p[2];
        float v[CHANS];
        cvt10(a, bq, cq, v);
        float s = score10(v);
        float mn = fmaxf(m, s);
        float scale = __expf(m - mn);
        float pp = __expf(s - mn);
        l = l * scale + pp;
        #pragma unroll
        for (int c = 0; c < CHANS; c++) acc[c] = acc[c] * scale + pp * v[c];
        m = mn;
    }

    // merge the two splits (partner 8 lanes away, same wave)
    float m2 = __shfl_xor(m, 8, 64);
    float l2 = __shfl_xor(l, 8, 64);
    float mn = fmaxf(m, m2);
    float sc1 = __expf(m - mn), sc2 = __expf(m2 - mn);
    float lt = l * sc1 + l2 * sc2;
    float accm[CHANS];
    #pragma unroll
    for (int c = 0; c < CHANS; c++) {
        float a2 = __shfl_xor(acc[c], 8, 64);
        accm[c] = acc[c] * sc1 + a2 * sc2;
    }
    if (split == 0) {
        float inv = 1.f / (lt + 1e-16f);
        #pragma unroll
        for (int c = 0; c < CHANS; c++) {
            float z = accm[c] * inv + bias[h * CHANS + c];
            y[(size_t)node * HC + h * CHANS + c] = (z > 0.f) ? z : (__expf(z) - 1.f);
        }
    }
}

// ---------------------------------------------------------------------------
extern "C" void kernel_launch(void* const* d_in, const int* in_sizes, int n_in,
                              void* d_out, int out_size, void* d_ws, size_t ws_size,
                              hipStream_t stream) {
    const float* x_in = (const float*)d_in[0];
    const void*  ei   = d_in[1];
    const float* Wl[3] = {(const float*)d_in[2], (const float*)d_in[6],  (const float*)d_in[10]};
    const float* Wr[3] = {(const float*)d_in[3], (const float*)d_in[7],  (const float*)d_in[11]};
    const float* At[3] = {(const float*)d_in[4], (const float*)d_in[8],  (const float*)d_in[12]};
    const float* Bi[3] = {(const float*)d_in[5], (const float*)d_in[9],  (const float*)d_in[13]};
    float* out = (float*)d_out;

    char* ws = (char*)d_ws;
    size_t off = 0;
    auto alloc = [&](size_t bytes) {
        void* p = ws + off;
        off += (bytes + 255) & ~(size_t)255;
        return p;
    };
    __half* xlh   = (__half*)alloc((size_t)N_NODES * PHL * sizeof(__half));
    float* xr     = (float*)alloc((size_t)N_NODES * HC * sizeof(float));
    float* buf    = (float*)alloc((size_t)N_NODES * HC * sizeof(float));
    int*   tmp    = (int*)alloc((size_t)E_TOT * sizeof(int));
    int*   adj    = (int*)alloc((size_t)E_TOT * sizeof(int));
    int*   hist   = (int*)alloc((size_t)NCHUNK * NBUCK * sizeof(int));
    int*   total  = (int*)alloc((size_t)NBUCK * sizeof(int));
    int*   bbase  = (int*)alloc((size_t)NBUCK * sizeof(int));
    int*   nstart = (int*)alloc((size_t)N_NODES * sizeof(int));
    int*   deg    = (int*)alloc((size_t)N_NODES * sizeof(int));
    int*   perm   = (int*)alloc((size_t)N_NODES * sizeof(int));
    int*   dh     = (int*)alloc(256 * sizeof(int));
    int*   dcur   = (int*)alloc(256 * sizeof(int));

    // --- build per-node CSR + degree-sorted permutation (once per launch) ---
    hist_kernel<<<NCHUNK, 256, 0, stream>>>(ei, hist);
    colscan_kernel<<<(NBUCK + 255) / 256, 256, 0, stream>>>(hist, total);
    scan_total_kernel<<<1, 1024, 0, stream>>>(total, bbase);
    scatter_sort_kernel<<<NCHUNK, 256, 0, stream>>>(ei, hist, bbase, tmp);
    node_sort_kernel<<<NBUCK, 256, 0, stream>>>(tmp, bbase, total, adj, nstart, deg);
    hipMemsetAsync(dh, 0, 256 * sizeof(int), stream);
    int nblocks = (N_NODES + 255) / 256;
    deghist_kernel<<<nblocks, 256, 0, stream>>>(deg, dh);
    degscan_kernel<<<1, 256, 0, stream>>>(dh, dcur);
    degscatter_kernel<<<nblocks, 256, 0, stream>>>(deg, dcur, perm);

    // --- 3 GATv2 layers ---
    int gemm_blocks = (N_NODES + 127) / 128;
    const float* cur = x_in;
    int din = F_IN;
    for (int layer = 0; layer < 3; layer++) {
        gemm_xlxr_kernel<<<gemm_blocks, 256, 0, stream>>>(cur, Wl[layer], Wr[layer],
                                                          din, xlh, xr);
        float* y = (layer == 2) ? out : buf;
        agg_kernel<<<NBUCK, 256, 0, stream>>>(xlh, xr, At[layer], Bi[layer],
                                              nstart, deg, adj, perm, y);
        cur = buf;
        din = HC;
    }
}